// Round 8
// baseline (435.181 us; speedup 1.0000x reference)
//
#include <hip/hip_runtime.h>

// PMField R8: R7 dataflow + latency hiding.
//  - __launch_bounds__(256,2): combined VGPR+AGPR budget 256 -> 2 blocks/CU
//    (R7: greedy 256 VGPR + AGPRs -> 1 block/CU, occupancy 11%, naked stalls).
//  - G-phase software-pipelined by one chunk with DOUBLE-BUFFERED wave-private
//    frag planes: w(c) written during chunk c; wf(c) read + G-MFMAs at end of
//    chunk c+1 -> LDS write->read round-trip (~240cyc x4/step) hidden under
//    the next S-phase (~1500cyc).
//  - cn2/mu as fp32 tables (no per-pair bf16 unpack; 128 VALU/step/lane saved)
//    and hoisted cz = zz+cn2+EPS -> per-pair elementwise 10 -> 8 ops.
// Layouts (HW-verified, R4-R7 passing): C/D col=lane&15,row=q*4+r;
// A[m=lane&15][k=q*8+j]; B = transpose-dual; w/z->B-frag scatter:
//   cw=16Mt+4q+r -> plane Kt=Mt>>1, lane m16+16*((2Mt+(q>>1))&3), uint 2(q&1)

#define STEPS 8
#define DTB   0.15f
#define EPSF  1e-4f

typedef short bf16x8 __attribute__((ext_vector_type(8)));
typedef float f32x4  __attribute__((ext_vector_type(4)));
union FragU { int4 i; bf16x8 h; };

__device__ __forceinline__ unsigned bf1(float a) {            // round-half-up
    return (__float_as_uint(a) + 0x8000u) >> 16;
}
__device__ __forceinline__ unsigned bfp(float lo, float hi) { // round pack
    return ((__float_as_uint(lo) + 0x8000u) >> 16) |
           ((__float_as_uint(hi) + 0x8000u) & 0xFFFF0000u);
}
__device__ __forceinline__ unsigned bfpt(float lo, float hi) { // trunc pack
    return (__float_as_uint(lo) >> 16) | (__float_as_uint(hi) & 0xFFFF0000u);
}
__device__ __forceinline__ float med3(float x, float lo, float hi) {
    return __builtin_amdgcn_fmed3f(x, lo, hi);
}

// d_ws layout:
//   int4 [0,    2048)  S-planes: ((c*4+Mt)*2+h)*64 + lane = bf16x8 of -2C[center][dims]
//   int4 [2048, 4096)  G-planes: ((Mt*4+c)*2+h)*64 + lane = bf16x8 of C^T[dim][centers]
//   f32  ws[16384+t]   cn2[t] = |c_t|^2   (t in [0,256))
//   f32  ws[16640+t]   mu[t]
__global__ void pm_prep(const float* __restrict__ centers,
                        const float* __restrict__ mus,
                        unsigned* __restrict__ ws) {
    const int gtid = blockIdx.x * 256 + threadIdx.x;
    if (gtid < 2048) {                       // S-plane frags
        const int c = gtid >> 9, Mt = (gtid >> 7) & 3, h = (gtid >> 6) & 1;
        const int L = gtid & 63, m16 = L & 15, q = L >> 4;
        const float* row = centers + (size_t)(64 * c + 16 * Mt + m16) * 64 + 32 * h + 8 * q;
        uint4 u;
        u.x = bfp(-2.f * row[0], -2.f * row[1]);
        u.y = bfp(-2.f * row[2], -2.f * row[3]);
        u.z = bfp(-2.f * row[4], -2.f * row[5]);
        u.w = bfp(-2.f * row[6], -2.f * row[7]);
        ((uint4*)ws)[gtid] = u;
    } else if (gtid < 4096) {                // G-plane frags (C^T)
        const int i = gtid - 2048;
        const int Mt = i >> 9, c = (i >> 7) & 3, h = (i >> 6) & 1;
        const int L = i & 63, m16 = L & 15, q = L >> 4;
        const float* base = centers + (size_t)(64 * c + 32 * h + 8 * q) * 64 + 16 * Mt + m16;
        uint4 u;
        u.x = bfp(base[0],   base[64]);
        u.y = bfp(base[128], base[192]);
        u.z = bfp(base[256], base[320]);
        u.w = bfp(base[384], base[448]);
        ((uint4*)ws)[gtid] = u;
    } else if (gtid < 4352) {                // cn2 / mu (fp32)
        const int t = gtid - 4096;
        const float* r = centers + (size_t)t * 64;
        float a0 = 0.f, a1 = 0.f, a2 = 0.f, a3 = 0.f;
#pragma unroll
        for (int d = 0; d < 64; d += 4) {
            a0 = fmaf(r[d],     r[d],     a0);
            a1 = fmaf(r[d + 1], r[d + 1], a1);
            a2 = fmaf(r[d + 2], r[d + 2], a2);
            a3 = fmaf(r[d + 3], r[d + 3], a3);
        }
        ((float*)ws)[16384 + t] = (a0 + a1) + (a2 + a3);
        ((float*)ws)[16640 + t] = mus[t];
    }
}

__global__ __launch_bounds__(256, 2)
void pm_main(const float* __restrict__ z_in,
             const unsigned* __restrict__ ws,
             float* __restrict__ z_out) {
    __shared__ int4 sA[2048];             // 32 KB: S-plane frags, block-shared
    __shared__ int4 sWF[4][2][4][64];     // 32 KB: [wave][buf][plane][lane]

    const int4* wsA  = (const int4*)ws;
    const int4* wsG  = wsA + 2048;
    const float* wsC = (const float*)ws + 16384;
    const float* wsU = (const float*)ws + 16640;

    const int tid  = threadIdx.x;
    const int lane = tid & 63;
    const int w    = tid >> 6;
    const int m16  = lane & 15;
    const int q    = lane >> 4;

    // copy S planes to LDS (lane-linear, coalesced, conflict-free)
#pragma unroll
    for (int i = 0; i < 8; ++i) sA[i * 256 + tid] = wsA[i * 256 + tid];
    __syncthreads();

    const int pbase = blockIdx.x * 128;   // 128 particles/block, 32/wave

    // z state in C/D layout: lane holds dims {16Mt+4q..+3} x particles {m16, m16+16}
    f32x4 z[4][2];
#pragma unroll
    for (int Mt = 0; Mt < 4; ++Mt)
#pragma unroll
        for (int Nt = 0; Nt < 2; ++Nt)
            z[Mt][Nt] = *(const f32x4*)(z_in + (size_t)(pbase + 32 * w + m16 + 16 * Nt) * 64
                                        + 16 * Mt + 4 * q);

    unsigned* wp = (unsigned*)&sWF[w][0][0][0];   // wave-private, 2 bufs x 1024 uints

#pragma unroll 1
    for (int s = 0; s < STEPS; ++s) {
        // zz per particle (butterfly over q groups), pre-add EPS
        float zze[2];
#pragma unroll
        for (int Nt = 0; Nt < 2; ++Nt) {
            float a = 0.f;
#pragma unroll
            for (int Mt = 0; Mt < 4; ++Mt)
#pragma unroll
                for (int r = 0; r < 4; ++r) a = fmaf(z[Mt][Nt][r], z[Mt][Nt][r], a);
            a += __shfl_xor(a, 16, 64);
            a += __shfl_xor(a, 32, 64);
            zze[Nt] = a + EPSF;
        }

        // z (C/D regs) -> B-frag planes in buf0 (read into regs before chunk0 overwrites)
#pragma unroll
        for (int Mt = 0; Mt < 4; ++Mt) {
            const int Kt = Mt >> 1;
            const int qt = (2 * Mt + (q >> 1)) & 3;
#pragma unroll
            for (int Nt = 0; Nt < 2; ++Nt) {
                const int pos = ((Kt * 2 + Nt) * 64 + m16 + 16 * qt) * 4 + 2 * (q & 1);
                *(uint2*)(wp + pos) = make_uint2(bfp(z[Mt][Nt][0], z[Mt][Nt][1]),
                                                 bfp(z[Mt][Nt][2], z[Mt][Nt][3]));
            }
        }
        FragU zf[2][2];
#pragma unroll
        for (int Kt = 0; Kt < 2; ++Kt)
#pragma unroll
            for (int Nt = 0; Nt < 2; ++Nt)
                zf[Kt][Nt].i = sWF[w][0][Kt * 2 + Nt][lane];   // lane-linear read

        f32x4 g[4][2];
#pragma unroll
        for (int Mt = 0; Mt < 4; ++Mt)
#pragma unroll
            for (int Nt = 0; Nt < 2; ++Nt) g[Mt][Nt] = (f32x4){0.f, 0.f, 0.f, 0.f};
        float nacc[2] = {0.f, 0.f}, swp[2] = {0.f, 0.f};

#pragma unroll
        for (int c = 0; c < 4; ++c) {          // 4 chunks x 64 centers
            unsigned* wcur = wp + (c & 1) * 1024;

            // ---- S-phase, fused per Mt; w -> plane buf (c&1) ----
#pragma unroll
            for (int Mt = 0; Mt < 4; ++Mt) {
                FragU a0, a1;
                a0.i = sA[((c * 4 + Mt) * 2 + 0) * 64 + lane];
                a1.i = sA[((c * 4 + Mt) * 2 + 1) * 64 + lane];
                f32x4 S[2];
#pragma unroll
                for (int Nt = 0; Nt < 2; ++Nt) {
                    f32x4 acc = (f32x4){0.f, 0.f, 0.f, 0.f};
                    acc = __builtin_amdgcn_mfma_f32_16x16x32_bf16(a0.h, zf[0][Nt].h, acc, 0, 0, 0);
                    acc = __builtin_amdgcn_mfma_f32_16x16x32_bf16(a1.h, zf[1][Nt].h, acc, 0, 0, 0);
                    S[Nt] = acc;   // S = -2*dot; row = center 64c+16Mt+4q+r, col = particle
                }

                const f32x4 cn2v = *(const f32x4*)(wsC + 64 * c + 16 * Mt + 4 * q);
                const f32x4 muv  = *(const f32x4*)(wsU + 64 * c + 16 * Mt + 4 * q);
                float cz[4][2];
#pragma unroll
                for (int r = 0; r < 4; ++r)
#pragma unroll
                    for (int Nt = 0; Nt < 2; ++Nt) cz[r][Nt] = zze[Nt] + cn2v[r];

                float wv[2][4];
#pragma unroll
                for (int r = 0; r < 4; ++r)
#pragma unroll
                    for (int Nt = 0; Nt < 2; ++Nt) {
                        float r2  = fmaxf(S[Nt][r] + cz[r][Nt], EPSF);
                        float rin = __builtin_amdgcn_rsqf(r2);
                        float mur = muv[r] * rin;
                        nacc[Nt] += mur;
                        float wval = mur * rin * rin;   // mu / r^3
                        swp[Nt] += wval;
                        wv[Nt][r] = wval;
                    }
                const int Kt = Mt >> 1;
                const int qt = (2 * Mt + (q >> 1)) & 3;
#pragma unroll
                for (int Nt = 0; Nt < 2; ++Nt) {
                    const int pos = ((Kt * 2 + Nt) * 64 + m16 + 16 * qt) * 4 + 2 * (q & 1);
                    *(uint2*)(wcur + pos) = make_uint2(bfpt(wv[Nt][0], wv[Nt][1]),
                                                       bfpt(wv[Nt][2], wv[Nt][3]));
                }
            }

            // ---- G-phase for PREVIOUS chunk (write->read latency hidden) ----
            if (c > 0) {
                const int cg = c - 1;
                FragU wf[2][2];
#pragma unroll
                for (int Kt = 0; Kt < 2; ++Kt)
#pragma unroll
                    for (int Nt = 0; Nt < 2; ++Nt)
                        wf[Kt][Nt].i = sWF[w][cg & 1][Kt * 2 + Nt][lane];
#pragma unroll
                for (int Mt = 0; Mt < 4; ++Mt) {
                    FragU ga0, ga1;
                    ga0.i = wsG[((Mt * 4 + cg) * 2 + 0) * 64 + lane];
                    ga1.i = wsG[((Mt * 4 + cg) * 2 + 1) * 64 + lane];
#pragma unroll
                    for (int Nt = 0; Nt < 2; ++Nt) {
                        g[Mt][Nt] = __builtin_amdgcn_mfma_f32_16x16x32_bf16(ga0.h, wf[0][Nt].h, g[Mt][Nt], 0, 0, 0);
                        g[Mt][Nt] = __builtin_amdgcn_mfma_f32_16x16x32_bf16(ga1.h, wf[1][Nt].h, g[Mt][Nt], 0, 0, 0);
                    }
                }
            }
        }
        // ---- tail: G-phase for chunk 3 ----
        {
            FragU wf[2][2];
#pragma unroll
            for (int Kt = 0; Kt < 2; ++Kt)
#pragma unroll
                for (int Nt = 0; Nt < 2; ++Nt)
                    wf[Kt][Nt].i = sWF[w][1][Kt * 2 + Nt][lane];
#pragma unroll
            for (int Mt = 0; Mt < 4; ++Mt) {
                FragU ga0, ga1;
                ga0.i = wsG[((Mt * 4 + 3) * 2 + 0) * 64 + lane];
                ga1.i = wsG[((Mt * 4 + 3) * 2 + 1) * 64 + lane];
#pragma unroll
                for (int Nt = 0; Nt < 2; ++Nt) {
                    g[Mt][Nt] = __builtin_amdgcn_mfma_f32_16x16x32_bf16(ga0.h, wf[0][Nt].h, g[Mt][Nt], 0, 0, 0);
                    g[Mt][Nt] = __builtin_amdgcn_mfma_f32_16x16x32_bf16(ga1.h, wf[1][Nt].h, g[Mt][Nt], 0, 0, 0);
                }
            }
        }

        // reduce n, sw across q groups; update z
        float tco[2], swf[2];
#pragma unroll
        for (int Nt = 0; Nt < 2; ++Nt) {
            float a = nacc[Nt];
            a += __shfl_xor(a, 16, 64);
            a += __shfl_xor(a, 32, 64);
            float b = swp[Nt];
            b += __shfl_xor(b, 16, 64);
            b += __shfl_xor(b, 32, 64);
            tco[Nt] = DTB * __builtin_amdgcn_rcpf(1.f + a);
            swf[Nt] = b;
        }
#pragma unroll
        for (int Mt = 0; Mt < 4; ++Mt)
#pragma unroll
            for (int Nt = 0; Nt < 2; ++Nt)
#pragma unroll
                for (int r = 0; r < 4; ++r) {
                    float gd = fmaf(-swf[Nt], z[Mt][Nt][r], g[Mt][Nt][r]);
                    z[Mt][Nt][r] = med3(fmaf(tco[Nt], gd, z[Mt][Nt][r]), -3.f, 3.f);
                }
    }

    // direct C/D-layout store
#pragma unroll
    for (int Mt = 0; Mt < 4; ++Mt)
#pragma unroll
        for (int Nt = 0; Nt < 2; ++Nt)
            *(f32x4*)(z_out + (size_t)(pbase + 32 * w + m16 + 16 * Nt) * 64
                      + 16 * Mt + 4 * q) = z[Mt][Nt];
}

extern "C" void kernel_launch(void* const* d_in, const int* in_sizes, int n_in,
                              void* d_out, int out_size, void* d_ws, size_t ws_size,
                              hipStream_t stream) {
    const float* z       = (const float*)d_in[0];
    const float* centers = (const float*)d_in[1];
    const float* mus     = (const float*)d_in[2];
    float* out           = (float*)d_out;
    unsigned* ws         = (unsigned*)d_ws;

    pm_prep<<<dim3(17), dim3(256), 0, stream>>>(centers, mus, ws);
    // 131072 particles / 128 per block (4 waves x 32) = 1024 blocks
    pm_main<<<dim3(1024), dim3(256), 0, stream>>>(z, ws, out);
}